// Round 1
// baseline (184.140 us; speedup 1.0000x reference)
//
#include <hip/hip_runtime.h>

typedef __bf16 bf16;
typedef __bf16 bf16x8 __attribute__((ext_vector_type(8)));
typedef __bf16 bf16x4 __attribute__((ext_vector_type(4)));
typedef float  f32x4  __attribute__((ext_vector_type(4)));

typedef __attribute__((address_space(1))) const void GASV;
typedef __attribute__((address_space(3))) void LASV;

__device__ __forceinline__ void gload16(const void* g, void* l) {
  __builtin_amdgcn_global_load_lds((GASV*)g, (LASV*)l, 16, 0, 0);
}

// ---------------- weight transpose + fp32->bf16 : out[n*K+k] = in[k*Cin+n] ----------------
__global__ __launch_bounds__(256) void wconv_t(const float* __restrict__ in,
                                               bf16* __restrict__ out,
                                               int lgK, int Cin, int total) {
  int idx = blockIdx.x * 256 + threadIdx.x;
  if (idx >= total) return;
  int K = 1 << lgK;
  int k = idx & (K - 1);
  int n = idx >> lgK;
  out[idx] = (bf16)in[(size_t)k * Cin + n];
}

// ---------------- layernorm rows of 256 (fp32 in -> bf16 out); 1 wave per row ----------------
__global__ __launch_bounds__(256) void ln_fwd(const float* __restrict__ x,
                                              const float* __restrict__ gam,
                                              const float* __restrict__ bet,
                                              bf16* __restrict__ out) {
  const int lane = threadIdx.x & 63;
  const int w = threadIdx.x >> 6;
  const size_t row = (size_t)blockIdx.x * 4 + w;
  const float4 v = *(const float4*)(x + row * 256 + lane * 4);
  float s1 = v.x + v.y + v.z + v.w;
  float s2 = v.x * v.x + v.y * v.y + v.z * v.z + v.w * v.w;
#pragma unroll
  for (int m = 1; m < 64; m <<= 1) {
    s1 += __shfl_xor(s1, m);
    s2 += __shfl_xor(s2, m);
  }
  const float mu = s1 * (1.0f / 256.0f);
  const float var = s2 * (1.0f / 256.0f) - mu * mu;
  const float rs = rsqrtf(var + 1e-5f);
  const float4 g4 = *(const float4*)(gam + lane * 4);
  const float4 b4 = *(const float4*)(bet + lane * 4);
  bf16x4 o;
  o[0] = (bf16)((v.x - mu) * rs * g4.x + b4.x);
  o[1] = (bf16)((v.y - mu) * rs * g4.y + b4.y);
  o[2] = (bf16)((v.z - mu) * rs * g4.z + b4.z);
  o[3] = (bf16)((v.w - mu) * rs * g4.w + b4.w);
  *(bf16x4*)(out + row * 256 + lane * 4) = o;
}

// ---------------- BT-form GEMM: C[r][c] = sum_k A[r][k]*Bt[c][k]  (128x128 tile, BK=64) ----
// EPI 0: bf16 out = acc + bias[c]                 (qkv Q/K)
// EPI 1: bf16 V^T scatter: out[r*2048 + (c>>11)*524288 + (c&2047)] = acc + bias[r]
// EPI 2: f32 out = acc + bias[c] + res[r*N+c]     (proj / fc2, residual fused)
// EPI 3: bf16 out = gelu(acc + bias[c])           (fc1, exact erf)
template <int EPI>
__global__ __launch_bounds__(256) void gemm_bt(const bf16* __restrict__ A,
                                               const bf16* __restrict__ Bt,
                                               const float* __restrict__ bias,
                                               const float* __restrict__ res,
                                               void* __restrict__ outp,
                                               int M, int N, int K) {
  __shared__ bf16 Al[2][8192];
  __shared__ bf16 Bl[2][8192];
  const int tid = threadIdx.x;
  const int lane = tid & 63;
  const int wid = tid >> 6;
  const int wm = wid >> 1, wn = wid & 1;
  const int nbm = M >> 7;
  const int bm = (int)blockIdx.x % nbm;
  const int bn = (int)blockIdx.x / nbm;
  const int m0 = bm << 7, n0 = bn << 7;
  const int nk = K >> 6;

  f32x4 acc[4][4];
#pragma unroll
  for (int i = 0; i < 4; ++i)
#pragma unroll
    for (int j = 0; j < 4; ++j) acc[i][j] = (f32x4){0.f, 0.f, 0.f, 0.f};

  auto stage = [&](int t, int s) {
    const int k0 = t << 6;
#pragma unroll
    for (int p = 0; p < 4; ++p) {
      const int idx = p * 4096 + tid * 16;   // byte within 16KB tile
      const int row = idx >> 7;              // 128B per row (64 bf16)
      const int colb = idx & 127;
      gload16((const char*)(A + ((size_t)(m0 + row) * K + k0)) + colb,
              (char*)&Al[s][0] + p * 4096 + ((tid >> 6) << 10));
      gload16((const char*)(Bt + ((size_t)(n0 + row) * K + k0)) + colb,
              (char*)&Bl[s][0] + p * 4096 + ((tid >> 6) << 10));
    }
  };

  stage(0, 0);
  asm volatile("s_waitcnt vmcnt(0)" ::: "memory");
  __syncthreads();

  for (int t = 0; t < nk; ++t) {
    if (t + 1 < nk) stage(t + 1, (t + 1) & 1);  // prefetch flies during MFMA
    const bf16* pa = &Al[t & 1][0] + (wm * 64 + (lane & 15)) * 64 + ((lane >> 4) << 3);
    const bf16* pb = &Bl[t & 1][0] + (wn * 64 + (lane & 15)) * 64 + ((lane >> 4) << 3);
    bf16x8 av[4][2], bv[4][2];
#pragma unroll
    for (int f = 0; f < 4; ++f)
#pragma unroll
      for (int ks = 0; ks < 2; ++ks) {
        av[f][ks] = *(const bf16x8*)(pa + f * 1024 + ks * 32);
        bv[f][ks] = *(const bf16x8*)(pb + f * 1024 + ks * 32);
      }
#pragma unroll
    for (int fm = 0; fm < 4; ++fm)
#pragma unroll
      for (int fn = 0; fn < 4; ++fn) {
        acc[fm][fn] = __builtin_amdgcn_mfma_f32_16x16x32_bf16(av[fm][0], bv[fn][0], acc[fm][fn], 0, 0, 0);
        acc[fm][fn] = __builtin_amdgcn_mfma_f32_16x16x32_bf16(av[fm][1], bv[fn][1], acc[fm][fn], 0, 0, 0);
      }
    asm volatile("s_waitcnt vmcnt(0)" ::: "memory");
    __syncthreads();
  }

#pragma unroll
  for (int fm = 0; fm < 4; ++fm)
#pragma unroll
    for (int fn = 0; fn < 4; ++fn) {
      const int r0 = m0 + wm * 64 + fm * 16 + ((lane >> 4) << 2);
      const int c = n0 + wn * 64 + fn * 16 + (lane & 15);
#pragma unroll
      for (int j = 0; j < 4; ++j) {
        const int r = r0 + j;
        const float v = acc[fm][fn][j];
        if constexpr (EPI == 0) {
          ((bf16*)outp)[(size_t)r * N + c] = (bf16)(v + bias[c]);
        } else if constexpr (EPI == 1) {
          ((bf16*)outp)[(size_t)r * 2048 + ((size_t)(c >> 11)) * 524288 + (c & 2047)] =
              (bf16)(v + bias[r]);
        } else if constexpr (EPI == 2) {
          ((float*)outp)[(size_t)r * N + c] = v + bias[c] + res[(size_t)r * N + c];
        } else {
          const float u = v + bias[c];
          ((bf16*)outp)[(size_t)r * N + c] = (bf16)(u * 0.5f * (1.0f + erff(u * 0.70710678118f)));
        }
      }
    }
}

// ---------------- flash attention, swapped QK^T, QBLK=64 (4 waves x 16 rows), KVBLK=64 -----
__global__ __launch_bounds__(256) void attn_fwd(const bf16* __restrict__ qk,
                                                const bf16* __restrict__ vT,
                                                bf16* __restrict__ ob) {
  __shared__ bf16 Kl[2][4096];
  __shared__ bf16 Vl[2][4096];
  const int tid = threadIdx.x;
  const int lane = tid & 63;
  const int w = tid >> 6;
  const int g = lane >> 4;
  const int qi = lane & 15;
  const int bh = blockIdx.x & 31;   // low bits -> same bh shares an XCD's L2
  const int qt = blockIdx.x >> 5;
  const int b = bh >> 2, h = bh & 3;

  // Q fragment (B-operand of S^T): col q = qi, k(d) = g*8 + j  (+32 for 2nd half of D)
  const size_t qrow = (size_t)b * 2048 + qt * 64 + w * 16 + qi;
  const bf16* qp = qk + qrow * 512 + h * 64 + g * 8;
  const bf16x8 qf0 = *(const bf16x8*)qp;
  const bf16x8 qf1 = *(const bf16x8*)(qp + 32);

  float mrun = -1e30f, lsum = 0.0f;
  f32x4 o[4];
#pragma unroll
  for (int i = 0; i < 4; ++i) o[i] = (f32x4){0.f, 0.f, 0.f, 0.f};

  const char* kbase = (const char*)qk + ((size_t)b * 2048) * 1024 + 512 + h * 128;
  const char* vbase = (const char*)vT + (size_t)bh * 262144;
  constexpr float CEXP = 0.125f * 1.44269504088896340736f;  // scale folded into exp2

  auto stage = [&](int t, int s) {
#pragma unroll
    for (int p = 0; p < 4; ++p) {
      const int idx = (p & 1) * 4096 + tid * 16;
      const int row = idx >> 7;
      const int colb = (idx ^ ((row & 7) << 4)) & 127;  // inverse-swizzled global source
      if (p < 2) {
        gload16(kbase + (size_t)(t * 64 + row) * 1024 + colb,
                (char*)&Kl[s][0] + (p & 1) * 4096 + ((tid >> 6) << 10));
      } else {
        gload16(vbase + (size_t)row * 4096 + t * 128 + colb,
                (char*)&Vl[s][0] + (p & 1) * 4096 + ((tid >> 6) << 10));
      }
    }
  };

  stage(0, 0);
  asm volatile("s_waitcnt vmcnt(0)" ::: "memory");
  __syncthreads();

  for (int t = 0; t < 32; ++t) {
    if (t < 31) stage(t + 1, (t + 1) & 1);
    const int s = t & 1;
    // ---- S^T = K·Q^T : rows kv, cols q ----
    f32x4 st[4];
#pragma unroll
    for (int fk = 0; fk < 4; ++fk) {
      const int kvr = fk * 16 + qi;
      const char* kb = (const char*)&Kl[s][0] + kvr * 128;
      const int sw = (kvr & 7) << 4;
      const bf16x8 k0 = *(const bf16x8*)(kb + ((g * 16) ^ sw));
      const bf16x8 k1 = *(const bf16x8*)(kb + ((64 + g * 16) ^ sw));
      f32x4 z = (f32x4){0.f, 0.f, 0.f, 0.f};
      st[fk] = __builtin_amdgcn_mfma_f32_16x16x32_bf16(k0, qf0, z, 0, 0, 0);
      st[fk] = __builtin_amdgcn_mfma_f32_16x16x32_bf16(k1, qf1, st[fk], 0, 0, 0);
    }
    // ---- online softmax; lane owns row q=qi; held kv = fk*16 + g*4 + j ----
    float mt = st[0][0];
#pragma unroll
    for (int fk = 0; fk < 4; ++fk)
#pragma unroll
      for (int j = 0; j < 4; ++j) mt = fmaxf(mt, st[fk][j]);
    mt = fmaxf(mt, __shfl_xor(mt, 16));
    mt = fmaxf(mt, __shfl_xor(mt, 32));
    const float mnew = fmaxf(mrun, mt);
    const float alpha = exp2f(CEXP * (mrun - mnew));
    float p[16];
    float ts = 0.f;
#pragma unroll
    for (int fk = 0; fk < 4; ++fk)
#pragma unroll
      for (int j = 0; j < 4; ++j) {
        const float pv = exp2f(CEXP * (st[fk][j] - mnew));
        p[fk * 4 + j] = pv;
        ts += pv;
      }
    ts += __shfl_xor(ts, 16);
    ts += __shfl_xor(ts, 32);
    lsum = lsum * alpha + ts;
    mrun = mnew;
    // rescale O (row q = g*4+j; alpha lives at lane q)
    float aj[4];
#pragma unroll
    for (int j = 0; j < 4; ++j) aj[j] = __shfl(alpha, g * 4 + j);
#pragma unroll
    for (int fd = 0; fd < 4; ++fd)
#pragma unroll
      for (int j = 0; j < 4; ++j) o[fd][j] *= aj[j];
    // pack P to bf16 pairs: pk[fk*2+jp] = (p[fk*4+2jp], p[fk*4+2jp+1])
    unsigned pk[8];
#pragma unroll
    for (int fk = 0; fk < 4; ++fk)
#pragma unroll
      for (int jp = 0; jp < 2; ++jp) {
        union { bf16 hh[2]; unsigned u; } cv;
        cv.hh[0] = (bf16)p[fk * 4 + 2 * jp];
        cv.hh[1] = (bf16)p[fk * 4 + 2 * jp + 1];
        pk[fk * 2 + jp] = cv.u;
      }
    // ---- PV: gather P into A-layout (row q = qi, k kv = g*8+jj) via 16 shfls ----
#pragma unroll
    for (int ksl = 0; ksl < 2; ++ksl) {
      union { bf16x8 v; unsigned u[4]; } pa;
#pragma unroll
      for (int pp = 0; pp < 4; ++pp) {
        const int src = ((2 * (g & 1) + (pp >> 1)) << 4) | qi;
        const unsigned r0 = (unsigned)__shfl((int)pk[(ksl * 2) * 2 + (pp & 1)], src);
        const unsigned r1 = (unsigned)__shfl((int)pk[(ksl * 2 + 1) * 2 + (pp & 1)], src);
        pa.u[pp] = (g >> 1) ? r1 : r0;
      }
#pragma unroll
      for (int fd = 0; fd < 4; ++fd) {
        const int dr = fd * 16 + qi;
        const char* vb = (const char*)&Vl[s][0] + dr * 128;
        const bf16x8 vv = *(const bf16x8*)(vb + ((ksl * 64 + g * 16) ^ ((dr & 7) << 4)));
        o[fd] = __builtin_amdgcn_mfma_f32_16x16x32_bf16(pa.v, vv, o[fd], 0, 0, 0);
      }
    }
    asm volatile("s_waitcnt vmcnt(0)" ::: "memory");
    __syncthreads();
  }

  const float inv = 1.0f / lsum;
  float ij[4];
#pragma unroll
  for (int j = 0; j < 4; ++j) ij[j] = __shfl(inv, g * 4 + j);
  const size_t orow0 = (size_t)b * 2048 + qt * 64 + w * 16 + g * 4;
#pragma unroll
  for (int fd = 0; fd < 4; ++fd)
#pragma unroll
    for (int j = 0; j < 4; ++j)
      ob[(orow0 + j) * 256 + h * 64 + fd * 16 + qi] = (bf16)(o[fd][j] * ij[j]);
}

extern "C" void kernel_launch(void* const* d_in, const int* in_sizes, int n_in,
                              void* d_out, int out_size, void* d_ws, size_t ws_size,
                              hipStream_t stream) {
  const float* x      = (const float*)d_in[0];
  const float* qkv_w  = (const float*)d_in[1];
  const float* qkv_b  = (const float*)d_in[2];
  const float* proj_w = (const float*)d_in[3];
  const float* proj_b = (const float*)d_in[4];
  const float* ln1_g  = (const float*)d_in[5];
  const float* ln1_b  = (const float*)d_in[6];
  const float* ln2_g  = (const float*)d_in[7];
  const float* ln2_b  = (const float*)d_in[8];
  const float* mlp_w1 = (const float*)d_in[9];
  const float* mlp_b1 = (const float*)d_in[10];
  const float* mlp_w2 = (const float*)d_in[11];
  const float* mlp_b2 = (const float*)d_in[12];
  float* out = (float*)d_out;

  char* ws = (char*)d_ws;
  bf16* Wtqkv = (bf16*)(ws);              // [768][256]   393216 B
  bf16* WtP   = (bf16*)(ws + 393216);     // [256][256]   131072 B
  bf16* Wt1   = (bf16*)(ws + 524288);     // [512][256]   262144 B
  bf16* Wt2   = (bf16*)(ws + 786432);     // [256][512]   262144 B
  bf16* h     = (bf16*)(ws + 1048576);    // [16384][256] 8388608 B
  bf16* qkb   = (bf16*)(ws + 9437184);    // [16384][512] 16777216 B
  bf16* vT    = (bf16*)(ws + 26214400);   // [32][64][2048] 8388608 B
  bf16* obuf  = (bf16*)(ws + 34603008);   // [16384][256] 8388608 B
  float* x2   = (float*)(ws + 42991616);  // [16384][256] 16777216 B  (total 59.8 MB)
  bf16* a1 = qkb;  // reuse (qkb dead after attn)
  bf16* h2 = h;    // reuse (h dead after V gemm)

  // weights -> bf16, transposed to [n][k]
  wconv_t<<<768, 256, 0, stream>>>(qkv_w, Wtqkv, 8, 768, 196608);
  wconv_t<<<256, 256, 0, stream>>>(proj_w, WtP, 8, 256, 65536);
  wconv_t<<<512, 256, 0, stream>>>(mlp_w1, Wt1, 8, 512, 131072);
  wconv_t<<<512, 256, 0, stream>>>(mlp_w2, Wt2, 9, 256, 131072);

  ln_fwd<<<4096, 256, 0, stream>>>(x, ln1_g, ln1_b, h);
  // Q,K: h @ W_qk  -> qkb [16384][512]
  gemm_bt<0><<<512, 256, 0, stream>>>(h, Wtqkv, qkv_b, nullptr, qkb, 16384, 512, 256);
  // V^T: Wv^T @ h^T -> vT [32][64][2048]  (swapped-operand GEMM, scatter epilogue)
  gemm_bt<1><<<256, 256, 0, stream>>>(Wtqkv + 512 * 256, h, qkv_b + 512, nullptr, vT, 256, 16384, 256);
  attn_fwd<<<1024, 256, 0, stream>>>(qkb, vT, obuf);
  // proj + residual -> x2 (f32)
  gemm_bt<2><<<256, 256, 0, stream>>>(obuf, WtP, proj_b, x, x2, 16384, 256, 256);
  ln_fwd<<<4096, 256, 0, stream>>>(x2, ln2_g, ln2_b, h2);
  // fc1 + gelu -> a1 (bf16)
  gemm_bt<3><<<512, 256, 0, stream>>>(h2, Wt1, mlp_b1, nullptr, a1, 16384, 512, 256);
  // fc2 + residual -> out (f32)
  gemm_bt<2><<<256, 256, 0, stream>>>(a1, Wt2, mlp_b2, x2, out, 16384, 256, 512);
}

// Round 2
// 179.062 us; speedup vs baseline: 1.0284x; 1.0284x over previous
//
#include <hip/hip_runtime.h>

typedef __bf16 bf16;
typedef __bf16 bf16x8 __attribute__((ext_vector_type(8)));
typedef __bf16 bf16x4 __attribute__((ext_vector_type(4)));
typedef float  f32x4  __attribute__((ext_vector_type(4)));
typedef unsigned u32x2 __attribute__((ext_vector_type(2)));

typedef __attribute__((address_space(1))) const void GASV;
typedef __attribute__((address_space(3))) void LASV;

__device__ __forceinline__ void gload16(const void* g, void* l) {
  __builtin_amdgcn_global_load_lds((GASV*)g, (LASV*)l, 16, 0, 0);
}

// ---------------- weight transpose + fp32->bf16 : out[n*K+k] = in[k*Cin+n] ----------------
__global__ __launch_bounds__(256) void wconv_t(const float* __restrict__ in,
                                               bf16* __restrict__ out,
                                               int lgK, int Cin, int total) {
  int idx = blockIdx.x * 256 + threadIdx.x;
  if (idx >= total) return;
  int K = 1 << lgK;
  int k = idx & (K - 1);
  int n = idx >> lgK;
  out[idx] = (bf16)in[(size_t)k * Cin + n];
}

// ---------------- layernorm rows of 256 (fp32 in -> bf16 out); 1 wave per row ----------------
__global__ __launch_bounds__(256) void ln_fwd(const float* __restrict__ x,
                                              const float* __restrict__ gam,
                                              const float* __restrict__ bet,
                                              bf16* __restrict__ out) {
  const int lane = threadIdx.x & 63;
  const int w = threadIdx.x >> 6;
  const size_t row = (size_t)blockIdx.x * 4 + w;
  const float4 v = *(const float4*)(x + row * 256 + lane * 4);
  float s1 = v.x + v.y + v.z + v.w;
  float s2 = v.x * v.x + v.y * v.y + v.z * v.z + v.w * v.w;
#pragma unroll
  for (int m = 1; m < 64; m <<= 1) {
    s1 += __shfl_xor(s1, m);
    s2 += __shfl_xor(s2, m);
  }
  const float mu = s1 * (1.0f / 256.0f);
  const float var = s2 * (1.0f / 256.0f) - mu * mu;
  const float rs = rsqrtf(var + 1e-5f);
  const float4 g4 = *(const float4*)(gam + lane * 4);
  const float4 b4 = *(const float4*)(bet + lane * 4);
  bf16x4 o;
  o[0] = (bf16)((v.x - mu) * rs * g4.x + b4.x);
  o[1] = (bf16)((v.y - mu) * rs * g4.y + b4.y);
  o[2] = (bf16)((v.z - mu) * rs * g4.z + b4.z);
  o[3] = (bf16)((v.w - mu) * rs * g4.w + b4.w);
  *(bf16x4*)(out + row * 256 + lane * 4) = o;
}

// ---------------- BT-form GEMM: C[r][c] = sum_k A[r][k]*Bt[c][k]  (128x128 tile, BK=64) ----
template <int EPI>
__global__ __launch_bounds__(256) void gemm_bt(const bf16* __restrict__ A,
                                               const bf16* __restrict__ Bt,
                                               const float* __restrict__ bias,
                                               const float* __restrict__ res,
                                               void* __restrict__ outp,
                                               int M, int N, int K) {
  __shared__ bf16 Al[2][8192];
  __shared__ bf16 Bl[2][8192];
  const int tid = threadIdx.x;
  const int lane = tid & 63;
  const int wid = tid >> 6;
  const int wm = wid >> 1, wn = wid & 1;
  const int nbm = M >> 7;
  const int bm = (int)blockIdx.x % nbm;
  const int bn = (int)blockIdx.x / nbm;
  const int m0 = bm << 7, n0 = bn << 7;
  const int nk = K >> 6;

  f32x4 acc[4][4];
#pragma unroll
  for (int i = 0; i < 4; ++i)
#pragma unroll
    for (int j = 0; j < 4; ++j) acc[i][j] = (f32x4){0.f, 0.f, 0.f, 0.f};

  auto stage = [&](int t, int s) {
    const int k0 = t << 6;
#pragma unroll
    for (int p = 0; p < 4; ++p) {
      const int idx = p * 4096 + tid * 16;   // byte within 16KB tile
      const int row = idx >> 7;              // 128B per row (64 bf16)
      const int colb = idx & 127;
      gload16((const char*)(A + ((size_t)(m0 + row) * K + k0)) + colb,
              (char*)&Al[s][0] + p * 4096 + ((tid >> 6) << 10));
      gload16((const char*)(Bt + ((size_t)(n0 + row) * K + k0)) + colb,
              (char*)&Bl[s][0] + p * 4096 + ((tid >> 6) << 10));
    }
  };

  stage(0, 0);
  asm volatile("s_waitcnt vmcnt(0)" ::: "memory");
  __syncthreads();

  for (int t = 0; t < nk; ++t) {
    if (t + 1 < nk) stage(t + 1, (t + 1) & 1);  // prefetch flies during MFMA
    const bf16* pa = &Al[t & 1][0] + (wm * 64 + (lane & 15)) * 64 + ((lane >> 4) << 3);
    const bf16* pb = &Bl[t & 1][0] + (wn * 64 + (lane & 15)) * 64 + ((lane >> 4) << 3);
    bf16x8 av[4][2], bv[4][2];
#pragma unroll
    for (int f = 0; f < 4; ++f)
#pragma unroll
      for (int ks = 0; ks < 2; ++ks) {
        av[f][ks] = *(const bf16x8*)(pa + f * 1024 + ks * 32);
        bv[f][ks] = *(const bf16x8*)(pb + f * 1024 + ks * 32);
      }
    __builtin_amdgcn_s_setprio(1);
#pragma unroll
    for (int fm = 0; fm < 4; ++fm)
#pragma unroll
      for (int fn = 0; fn < 4; ++fn) {
        acc[fm][fn] = __builtin_amdgcn_mfma_f32_16x16x32_bf16(av[fm][0], bv[fn][0], acc[fm][fn], 0, 0, 0);
        acc[fm][fn] = __builtin_amdgcn_mfma_f32_16x16x32_bf16(av[fm][1], bv[fn][1], acc[fm][fn], 0, 0, 0);
      }
    __builtin_amdgcn_s_setprio(0);
    asm volatile("s_waitcnt vmcnt(0)" ::: "memory");
    __syncthreads();
  }

#pragma unroll
  for (int fm = 0; fm < 4; ++fm)
#pragma unroll
    for (int fn = 0; fn < 4; ++fn) {
      const int r0 = m0 + wm * 64 + fm * 16 + ((lane >> 4) << 2);
      const int c = n0 + wn * 64 + fn * 16 + (lane & 15);
#pragma unroll
      for (int j = 0; j < 4; ++j) {
        const int r = r0 + j;
        const float v = acc[fm][fn][j];
        if constexpr (EPI == 0) {
          ((bf16*)outp)[(size_t)r * N + c] = (bf16)(v + bias[c]);
        } else if constexpr (EPI == 1) {
          ((bf16*)outp)[(size_t)r * 2048 + ((size_t)(c >> 11)) * 524288 + (c & 2047)] =
              (bf16)(v + bias[r]);
        } else if constexpr (EPI == 2) {
          ((float*)outp)[(size_t)r * N + c] = v + bias[c] + res[(size_t)r * N + c];
        } else {
          const float u = v + bias[c];
          ((bf16*)outp)[(size_t)r * N + c] = (bf16)(u * 0.5f * (1.0f + erff(u * 0.70710678118f)));
        }
      }
    }
}

// ---------------- flash attention, swapped QK^T + swapped PV (O^T), fragment-major LDS -----
// 4 waves x 16 q-rows, KVBLK=64. K/V staged in MFMA-fragment order via per-lane
// pre-permuted global_load_lds sources -> all ds_reads are base+lane*16+imm (0 conflicts).
__global__ __launch_bounds__(256) void attn_fwd(const bf16* __restrict__ qk,
                                                const bf16* __restrict__ vT,
                                                bf16* __restrict__ ob) {
  __shared__ bf16 Kl[2][4096];   // slot(fk,half,g,qi): K[fk*16+qi][half*32+g*8 ..+7]
  __shared__ bf16 Vl[2][4096];   // slot(fd,ksl,g,qi): V^T[fd*16+qi][ksl*32+g*8 ..+7]
  __shared__ bf16 Pl[4][1024];   // per-wave P^T in B-frag-linear order (2KB each)
  const int tid = threadIdx.x;
  const int lane = tid & 63;
  const int w = tid >> 6;
  const int g = lane >> 4;
  const int qi = lane & 15;
  const int bh = blockIdx.x & 31;   // low bits -> same bh shares an XCD's L2
  const int qt = blockIdx.x >> 5;
  const int b = bh >> 2, h = bh & 3;

  // Q fragment (B-operand of S^T): col q = qi, k(d) = half*32 + g*8 + j
  const size_t qrow = (size_t)b * 2048 + qt * 64 + w * 16 + qi;
  const bf16* qp = qk + qrow * 512 + h * 64 + g * 8;
  const bf16x8 qf0 = *(const bf16x8*)qp;
  const bf16x8 qf1 = *(const bf16x8*)(qp + 32);

  float mrun = 0.0f, lsum = 0.0f;
  f32x4 o[4];
#pragma unroll
  for (int i = 0; i < 4; ++i) o[i] = (f32x4){0.f, 0.f, 0.f, 0.f};

  const char* kbase = (const char*)qk + ((size_t)b * 2048) * 1024 + 512 + h * 128;
  const char* vbase = (const char*)vT + (size_t)bh * 262144;
  constexpr float CEXP = 0.125f * 1.44269504088896340736f;  // scale folded into exp2
  constexpr float THR = 8.0f / CEXP;                        // defer-max threshold

  // per-lane pre-permuted staging source offsets (bytes), constant across tiles:
  // dest slot i*256 + w*64 + lane  ->  (fk = i*2 + (w>>1), half = w&1, g, qi)
  int koff[2], voff[2];
#pragma unroll
  for (int i = 0; i < 2; ++i) {
    const int fk = i * 2 + (w >> 1);
    const int half = w & 1;
    koff[i] = (fk * 16 + qi) * 1024 + half * 64 + g * 16;
    voff[i] = (fk * 16 + qi) * 4096 + half * 64 + g * 16;
  }
  // per-lane P_lds write addresses (b64 pair per fk), within this wave's 2KB slab
  char* const pw = (char*)&Pl[w][0];
  int paddr[4];
#pragma unroll
  for (int fk = 0; fk < 4; ++fk)
    paddr[fk] = (fk >> 1) * 1024 + ((fk & 1) * 2 + (g >> 1)) * 256 + qi * 16 + ((g & 1) * 2) * 4;
  const char* const pr = (const char*)&Pl[w][0] + lane * 16;

  auto stage = [&](int t, int s) {
    const size_t kt = (size_t)t * 65536;
    const size_t vt = (size_t)t * 128;
#pragma unroll
    for (int i = 0; i < 2; ++i) {
      gload16(kbase + kt + koff[i], (char*)&Kl[s][0] + i * 4096 + w * 1024);
      gload16(vbase + vt + voff[i], (char*)&Vl[s][0] + i * 4096 + w * 1024);
    }
  };

  stage(0, 0);
  asm volatile("s_waitcnt vmcnt(0)" ::: "memory");
  __syncthreads();

  for (int t = 0; t < 32; ++t) {
    if (t < 31) stage(t + 1, (t + 1) & 1);
    const int s = t & 1;
    // ---- S^T = K·Q^T : linear frag reads (base + lane*16 + imm) ----
    const char* kb = (const char*)&Kl[s][0] + lane * 16;
    f32x4 st[4];
    __builtin_amdgcn_s_setprio(1);
#pragma unroll
    for (int fk = 0; fk < 4; ++fk) {
      const bf16x8 k0 = *(const bf16x8*)(kb + fk * 2048);
      const bf16x8 k1 = *(const bf16x8*)(kb + fk * 2048 + 1024);
      f32x4 z = (f32x4){0.f, 0.f, 0.f, 0.f};
      st[fk] = __builtin_amdgcn_mfma_f32_16x16x32_bf16(k0, qf0, z, 0, 0, 0);
      st[fk] = __builtin_amdgcn_mfma_f32_16x16x32_bf16(k1, qf1, st[fk], 0, 0, 0);
    }
    __builtin_amdgcn_s_setprio(0);
    // ---- online softmax; lane owns col q=qi; held kv = fk*16 + g*4 + j ----
    float pmax = st[0][0];
#pragma unroll
    for (int fk = 0; fk < 4; ++fk)
#pragma unroll
      for (int j = 0; j < 4; ++j) pmax = fmaxf(pmax, st[fk][j]);
    if (!__all(pmax <= mrun + THR)) {   // rare rescale path
      float mt = fmaxf(pmax, __shfl_xor(pmax, 16));
      mt = fmaxf(mt, __shfl_xor(mt, 32));
      const float mnew = fmaxf(mrun, mt);
      const float alpha = exp2f(CEXP * (mrun - mnew));
      lsum *= alpha;
#pragma unroll
      for (int fd = 0; fd < 4; ++fd)
#pragma unroll
        for (int j = 0; j < 4; ++j) o[fd][j] *= alpha;
      mrun = mnew;
    }
    const float negcm = -CEXP * mrun;
    float ts = 0.f;
    unsigned pk[8];
#pragma unroll
    for (int fk = 0; fk < 4; ++fk)
#pragma unroll
      for (int jp = 0; jp < 2; ++jp) {
        const float p0 = exp2f(fmaf(st[fk][2 * jp], CEXP, negcm));
        const float p1 = exp2f(fmaf(st[fk][2 * jp + 1], CEXP, negcm));
        ts += p0 + p1;
        union { bf16 h2[2]; unsigned u; } cv;
        cv.h2[0] = (bf16)p0;
        cv.h2[1] = (bf16)p1;
        pk[fk * 2 + jp] = cv.u;
      }
    ts += __shfl_xor(ts, 16);
    ts += __shfl_xor(ts, 32);
    lsum += ts;
    // ---- redistribute P^T to B-frag order via per-wave LDS (4x b64 write, 2x b128 read) ----
#pragma unroll
    for (int fk = 0; fk < 4; ++fk) {
      u32x2 pr2;
      pr2[0] = pk[fk * 2];
      pr2[1] = pk[fk * 2 + 1];
      *(u32x2*)(pw + paddr[fk]) = pr2;
    }
    const bf16x8 pa0 = *(const bf16x8*)(pr);
    const bf16x8 pa1 = *(const bf16x8*)(pr + 1024);
    // ---- O^T += V^T · P^T : linear frag reads ----
    const char* vb = (const char*)&Vl[s][0] + lane * 16;
    __builtin_amdgcn_s_setprio(1);
#pragma unroll
    for (int fd = 0; fd < 4; ++fd) {
      const bf16x8 v0 = *(const bf16x8*)(vb + fd * 2048);
      const bf16x8 v1 = *(const bf16x8*)(vb + fd * 2048 + 1024);
      o[fd] = __builtin_amdgcn_mfma_f32_16x16x32_bf16(v0, pa0, o[fd], 0, 0, 0);
      o[fd] = __builtin_amdgcn_mfma_f32_16x16x32_bf16(v1, pa1, o[fd], 0, 0, 0);
    }
    __builtin_amdgcn_s_setprio(0);
    asm volatile("s_waitcnt vmcnt(0)" ::: "memory");
    __syncthreads();
  }

  // O^T C-layout: col q = qi (lane-local lsum), rows d = fd*16 + g*4 + j
  const float inv = 1.0f / lsum;
  bf16* const orow = ob + qrow * 256 + h * 64 + g * 4;
#pragma unroll
  for (int fd = 0; fd < 4; ++fd) {
    bf16x4 ov;
#pragma unroll
    for (int j = 0; j < 4; ++j) ov[j] = (bf16)(o[fd][j] * inv);
    *(bf16x4*)(orow + fd * 16) = ov;
  }
}

extern "C" void kernel_launch(void* const* d_in, const int* in_sizes, int n_in,
                              void* d_out, int out_size, void* d_ws, size_t ws_size,
                              hipStream_t stream) {
  const float* x      = (const float*)d_in[0];
  const float* qkv_w  = (const float*)d_in[1];
  const float* qkv_b  = (const float*)d_in[2];
  const float* proj_w = (const float*)d_in[3];
  const float* proj_b = (const float*)d_in[4];
  const float* ln1_g  = (const float*)d_in[5];
  const float* ln1_b  = (const float*)d_in[6];
  const float* ln2_g  = (const float*)d_in[7];
  const float* ln2_b  = (const float*)d_in[8];
  const float* mlp_w1 = (const float*)d_in[9];
  const float* mlp_b1 = (const float*)d_in[10];
  const float* mlp_w2 = (const float*)d_in[11];
  const float* mlp_b2 = (const float*)d_in[12];
  float* out = (float*)d_out;

  char* ws = (char*)d_ws;
  bf16* Wtqkv = (bf16*)(ws);              // [768][256]   393216 B
  bf16* WtP   = (bf16*)(ws + 393216);     // [256][256]   131072 B
  bf16* Wt1   = (bf16*)(ws + 524288);     // [512][256]   262144 B
  bf16* Wt2   = (bf16*)(ws + 786432);     // [256][512]   262144 B
  bf16* h     = (bf16*)(ws + 1048576);    // [16384][256] 8388608 B
  bf16* qkb   = (bf16*)(ws + 9437184);    // [16384][512] 16777216 B
  bf16* vT    = (bf16*)(ws + 26214400);   // [32][64][2048] 8388608 B
  bf16* obuf  = (bf16*)(ws + 34603008);   // [16384][256] 8388608 B
  float* x2   = (float*)(ws + 42991616);  // [16384][256] 16777216 B  (total 59.8 MB)
  bf16* a1 = qkb;  // reuse (qkb dead after attn)
  bf16* h2 = h;    // reuse (h dead after V gemm)

  // weights -> bf16, transposed to [n][k]
  wconv_t<<<768, 256, 0, stream>>>(qkv_w, Wtqkv, 8, 768, 196608);
  wconv_t<<<256, 256, 0, stream>>>(proj_w, WtP, 8, 256, 65536);
  wconv_t<<<512, 256, 0, stream>>>(mlp_w1, Wt1, 8, 512, 131072);
  wconv_t<<<512, 256, 0, stream>>>(mlp_w2, Wt2, 9, 256, 131072);

  ln_fwd<<<4096, 256, 0, stream>>>(x, ln1_g, ln1_b, h);
  // Q,K: h @ W_qk  -> qkb [16384][512]
  gemm_bt<0><<<512, 256, 0, stream>>>(h, Wtqkv, qkv_b, nullptr, qkb, 16384, 512, 256);
  // V^T: Wv^T @ h^T -> vT [32][64][2048]  (swapped-operand GEMM, scatter epilogue)
  gemm_bt<1><<<256, 256, 0, stream>>>(Wtqkv + 512 * 256, h, qkv_b + 512, nullptr, vT, 256, 16384, 256);
  attn_fwd<<<1024, 256, 0, stream>>>(qkb, vT, obuf);
  // proj + residual -> x2 (f32)
  gemm_bt<2><<<256, 256, 0, stream>>>(obuf, WtP, proj_b, x, x2, 16384, 256, 256);
  ln_fwd<<<4096, 256, 0, stream>>>(x2, ln2_g, ln2_b, h2);
  // fc1 + gelu -> a1 (bf16)
  gemm_bt<3><<<512, 256, 0, stream>>>(h2, Wt1, mlp_b1, nullptr, a1, 16384, 512, 256);
  // fc2 + residual -> out (f32)
  gemm_bt<2><<<256, 256, 0, stream>>>(a1, Wt2, mlp_b2, x2, out, 16384, 256, 512);
}

// Round 3
// 171.357 us; speedup vs baseline: 1.0746x; 1.0450x over previous
//
#include <hip/hip_runtime.h>

typedef __bf16 bf16;
typedef __bf16 bf16x8 __attribute__((ext_vector_type(8)));
typedef __bf16 bf16x4 __attribute__((ext_vector_type(4)));
typedef float  f32x4  __attribute__((ext_vector_type(4)));
typedef unsigned u32x2 __attribute__((ext_vector_type(2)));

typedef __attribute__((address_space(1))) const void GASV;
typedef __attribute__((address_space(3))) void LASV;

__device__ __forceinline__ void gload16(const void* g, void* l) {
  __builtin_amdgcn_global_load_lds((GASV*)g, (LASV*)l, 16, 0, 0);
}

// ---------------- all four weight transposes fp32->bf16 in one launch ----------------
__global__ __launch_bounds__(256) void wconv_all(const float* __restrict__ qkv_w,
                                                 const float* __restrict__ proj_w,
                                                 const float* __restrict__ w1,
                                                 const float* __restrict__ w2,
                                                 bf16* __restrict__ Wtqkv,
                                                 bf16* __restrict__ WtP,
                                                 bf16* __restrict__ Wt1,
                                                 bf16* __restrict__ Wt2) {
  const int idx = blockIdx.x * 256 + threadIdx.x;   // 524288 total
  if (idx < 196608) {
    const int k = idx & 255, n = idx >> 8;
    Wtqkv[idx] = (bf16)qkv_w[k * 768 + n];
  } else if (idx < 262144) {
    const int i = idx - 196608, k = i & 255, n = i >> 8;
    WtP[i] = (bf16)proj_w[k * 256 + n];
  } else if (idx < 393216) {
    const int i = idx - 262144, k = i & 255, n = i >> 8;
    Wt1[i] = (bf16)w1[k * 512 + n];
  } else {
    const int i = idx - 393216, k = i & 511, n = i >> 9;
    Wt2[i] = (bf16)w2[k * 256 + n];
  }
}

// ---------------- layernorm rows of 256 (fp32 in -> bf16 out); 1 wave per row ----------------
__global__ __launch_bounds__(256) void ln_fwd(const float* __restrict__ x,
                                              const float* __restrict__ gam,
                                              const float* __restrict__ bet,
                                              bf16* __restrict__ out) {
  const int lane = threadIdx.x & 63;
  const int w = threadIdx.x >> 6;
  const size_t row = (size_t)blockIdx.x * 4 + w;
  const float4 v = *(const float4*)(x + row * 256 + lane * 4);
  float s1 = v.x + v.y + v.z + v.w;
  float s2 = v.x * v.x + v.y * v.y + v.z * v.z + v.w * v.w;
#pragma unroll
  for (int m = 1; m < 64; m <<= 1) {
    s1 += __shfl_xor(s1, m);
    s2 += __shfl_xor(s2, m);
  }
  const float mu = s1 * (1.0f / 256.0f);
  const float var = s2 * (1.0f / 256.0f) - mu * mu;
  const float rs = rsqrtf(var + 1e-5f);
  const float4 g4 = *(const float4*)(gam + lane * 4);
  const float4 b4 = *(const float4*)(bet + lane * 4);
  bf16x4 o;
  o[0] = (bf16)((v.x - mu) * rs * g4.x + b4.x);
  o[1] = (bf16)((v.y - mu) * rs * g4.y + b4.y);
  o[2] = (bf16)((v.z - mu) * rs * g4.z + b4.z);
  o[3] = (bf16)((v.w - mu) * rs * g4.w + b4.w);
  *(bf16x4*)(out + row * 256 + lane * 4) = o;
}

// ---------------- BT-form GEMM: C[r][c] = sum_k A[r][k]*Bt[c][k]  (128x128 tile, BK=64) ----
template <int EPI>
__global__ __launch_bounds__(256) void gemm_bt(const bf16* __restrict__ A,
                                               const bf16* __restrict__ Bt,
                                               const float* __restrict__ bias,
                                               const float* __restrict__ res,
                                               void* __restrict__ outp,
                                               int M, int N, int K) {
  __shared__ bf16 Al[2][8192];
  __shared__ bf16 Bl[2][8192];
  const int tid = threadIdx.x;
  const int lane = tid & 63;
  const int wid = tid >> 6;
  const int wm = wid >> 1, wn = wid & 1;
  const int nbm = M >> 7;
  const int bm = (int)blockIdx.x % nbm;
  const int bn = (int)blockIdx.x / nbm;
  const int m0 = bm << 7, n0 = bn << 7;
  const int nk = K >> 6;

  f32x4 acc[4][4];
#pragma unroll
  for (int i = 0; i < 4; ++i)
#pragma unroll
    for (int j = 0; j < 4; ++j) acc[i][j] = (f32x4){0.f, 0.f, 0.f, 0.f};

  auto stage = [&](int t, int s) {
    const int k0 = t << 6;
#pragma unroll
    for (int p = 0; p < 4; ++p) {
      const int idx = p * 4096 + tid * 16;   // byte within 16KB tile
      const int row = idx >> 7;              // 128B per row (64 bf16)
      const int colb = idx & 127;
      gload16((const char*)(A + ((size_t)(m0 + row) * K + k0)) + colb,
              (char*)&Al[s][0] + p * 4096 + ((tid >> 6) << 10));
      gload16((const char*)(Bt + ((size_t)(n0 + row) * K + k0)) + colb,
              (char*)&Bl[s][0] + p * 4096 + ((tid >> 6) << 10));
    }
  };

  stage(0, 0);
  asm volatile("s_waitcnt vmcnt(0)" ::: "memory");
  __syncthreads();

  for (int t = 0; t < nk; ++t) {
    if (t + 1 < nk) stage(t + 1, (t + 1) & 1);  // prefetch flies during MFMA
    const bf16* pa = &Al[t & 1][0] + (wm * 64 + (lane & 15)) * 64 + ((lane >> 4) << 3);
    const bf16* pb = &Bl[t & 1][0] + (wn * 64 + (lane & 15)) * 64 + ((lane >> 4) << 3);
    bf16x8 av[4][2], bv[4][2];
#pragma unroll
    for (int f = 0; f < 4; ++f)
#pragma unroll
      for (int ks = 0; ks < 2; ++ks) {
        av[f][ks] = *(const bf16x8*)(pa + f * 1024 + ks * 32);
        bv[f][ks] = *(const bf16x8*)(pb + f * 1024 + ks * 32);
      }
    __builtin_amdgcn_s_setprio(1);
#pragma unroll
    for (int fm = 0; fm < 4; ++fm)
#pragma unroll
      for (int fn = 0; fn < 4; ++fn) {
        acc[fm][fn] = __builtin_amdgcn_mfma_f32_16x16x32_bf16(av[fm][0], bv[fn][0], acc[fm][fn], 0, 0, 0);
        acc[fm][fn] = __builtin_amdgcn_mfma_f32_16x16x32_bf16(av[fm][1], bv[fn][1], acc[fm][fn], 0, 0, 0);
      }
    __builtin_amdgcn_s_setprio(0);
    asm volatile("s_waitcnt vmcnt(0)" ::: "memory");
    __syncthreads();
  }

#pragma unroll
  for (int fm = 0; fm < 4; ++fm)
#pragma unroll
    for (int fn = 0; fn < 4; ++fn) {
      const int r0 = m0 + wm * 64 + fm * 16 + ((lane >> 4) << 2);
      const int c = n0 + wn * 64 + fn * 16 + (lane & 15);
#pragma unroll
      for (int j = 0; j < 4; ++j) {
        const int r = r0 + j;
        const float v = acc[fm][fn][j];
        if constexpr (EPI == 0) {
          ((bf16*)outp)[(size_t)r * N + c] = (bf16)(v + bias[c]);
        } else if constexpr (EPI == 1) {
          ((bf16*)outp)[(size_t)r * 2048 + ((size_t)(c >> 11)) * 524288 + (c & 2047)] =
              (bf16)(v + bias[r]);
        } else if constexpr (EPI == 2) {
          ((float*)outp)[(size_t)r * N + c] = v + bias[c] + res[(size_t)r * N + c];
        } else {
          const float u = v + bias[c];
          ((bf16*)outp)[(size_t)r * N + c] = (bf16)(u * 0.5f * (1.0f + erff(u * 0.70710678118f)));
        }
      }
    }
}

// ---------------- flash attention v3: QBLK=128 (4 waves x 32 q), KVBLK=64 ------------------
// Triple-buffered K/V (counted vmcnt keeps prefetch in flight across raw s_barrier),
// fragment-major LDS (all ds_reads linear), swapped QK^T + swapped PV (O^T),
// per-lane deferred lsum, defer-max rescale.
__global__ __launch_bounds__(256) void attn_fwd(const bf16* __restrict__ qk,
                                                const bf16* __restrict__ vT,
                                                bf16* __restrict__ ob) {
  __shared__ bf16 Kl[3][4096];   // slot: frag-major K tile (8KB)
  __shared__ bf16 Vl[3][4096];   // slot: frag-major V^T tile (8KB)
  __shared__ bf16 Pl[4][2048];   // per-wave P^T, B-frag-linear, 4KB each
  const int tid = threadIdx.x;
  const int lane = tid & 63;
  const int w = tid >> 6;
  const int g = lane >> 4;
  const int qi = lane & 15;
  const int bh = blockIdx.x & 31;   // low bits -> same bh shares an XCD's L2
  const int qt = blockIdx.x >> 5;   // 16 q-tiles of 128
  const int b = bh >> 2, h = bh & 3;

  // Q fragments f=0,1 (B-operand of S^T): col q = f*16+qi, k(d) = half*32 + g*8 + j
  const size_t qrow0 = (size_t)b * 2048 + qt * 128 + w * 32 + qi;
  bf16x8 qf[2][2];
#pragma unroll
  for (int f = 0; f < 2; ++f) {
    const bf16* qp = qk + (qrow0 + f * 16) * 512 + h * 64 + g * 8;
    qf[f][0] = *(const bf16x8*)qp;
    qf[f][1] = *(const bf16x8*)(qp + 32);
  }

  float mrun[2] = {0.f, 0.f};
  float lsum[2] = {0.f, 0.f};   // per-lane partial (over this lane's kv slice)
  f32x4 o[4][2];
#pragma unroll
  for (int i = 0; i < 4; ++i)
#pragma unroll
    for (int f = 0; f < 2; ++f) o[i][f] = (f32x4){0.f, 0.f, 0.f, 0.f};

  constexpr float CEXP = 0.125f * 1.44269504088896340736f;
  constexpr float THR = 8.0f / CEXP;

  // staging sources (frag-major pre-permute), advanced per tile
  const char* kbase = (const char*)qk + ((size_t)b * 2048) * 1024 + 512 + h * 128;
  const char* vbase = (const char*)vT + (size_t)bh * 262144;
  const char* ks[2];
  const char* vs[2];
#pragma unroll
  for (int i = 0; i < 2; ++i) {
    const int fk = i * 2 + (w >> 1);
    const int half = w & 1;
    ks[i] = kbase + (fk * 16 + qi) * 1024 + half * 64 + g * 16;
    vs[i] = vbase + (size_t)(fk * 16 + qi) * 4096 + half * 64 + g * 16;
  }
  // P LDS addressing
  char* const pw = (char*)&Pl[w][0];
  int paddr[4];
#pragma unroll
  for (int fk = 0; fk < 4; ++fk)
    paddr[fk] = (fk >> 1) * 2048 + ((fk & 1) * 2 + (g >> 1)) * 256 + qi * 16 + (g & 1) * 8;
  const char* const prd = (const char*)&Pl[w][0] + lane * 16;

  auto stage = [&](int slot) {
    char* kd = (char*)&Kl[0][0] + slot * 8192 + w * 1024;
    char* vd = (char*)&Vl[0][0] + slot * 8192 + w * 1024;
    gload16(ks[0], kd);
    gload16(ks[1], kd + 4096);
    gload16(vs[0], vd);
    gload16(vs[1], vd + 4096);
    ks[0] += 65536; ks[1] += 65536;
    vs[0] += 128;   vs[1] += 128;
  };

  stage(0);
  stage(1);
  asm volatile("s_waitcnt vmcnt(4)" ::: "memory");   // tile0 done, tile1 in flight
  __builtin_amdgcn_s_barrier();

  int slot = 0, slot2 = 2;
  for (int t = 0; t < 32; ++t) {
    if (t < 30) stage(slot2);
    // ---- S^T = K·Q^T : linear frag reads ----
    const char* kb = (const char*)&Kl[0][0] + slot * 8192 + lane * 16;
    f32x4 st[4][2];
    __builtin_amdgcn_s_setprio(1);
#pragma unroll
    for (int fk = 0; fk < 4; ++fk) {
      const bf16x8 k0 = *(const bf16x8*)(kb + fk * 2048);
      const bf16x8 k1 = *(const bf16x8*)(kb + fk * 2048 + 1024);
#pragma unroll
      for (int f = 0; f < 2; ++f) {
        f32x4 z = (f32x4){0.f, 0.f, 0.f, 0.f};
        st[fk][f] = __builtin_amdgcn_mfma_f32_16x16x32_bf16(k0, qf[f][0], z, 0, 0, 0);
        st[fk][f] = __builtin_amdgcn_mfma_f32_16x16x32_bf16(k1, qf[f][1], st[fk][f], 0, 0, 0);
      }
    }
    __builtin_amdgcn_s_setprio(0);
    // ---- online softmax (lane-local col q = f*16+qi; kv slice = fk*16+g*4+j) ----
    float pmax[2];
#pragma unroll
    for (int f = 0; f < 2; ++f) {
      float m0 = fmaxf(fmaxf(st[0][f][0], st[0][f][1]), fmaxf(st[0][f][2], st[0][f][3]));
      float m1 = fmaxf(fmaxf(st[1][f][0], st[1][f][1]), fmaxf(st[1][f][2], st[1][f][3]));
      float m2 = fmaxf(fmaxf(st[2][f][0], st[2][f][1]), fmaxf(st[2][f][2], st[2][f][3]));
      float m3 = fmaxf(fmaxf(st[3][f][0], st[3][f][1]), fmaxf(st[3][f][2], st[3][f][3]));
      pmax[f] = fmaxf(fmaxf(m0, m1), fmaxf(m2, m3));
    }
    if (!__all(pmax[0] <= mrun[0] + THR && pmax[1] <= mrun[1] + THR)) {  // rare
#pragma unroll
      for (int f = 0; f < 2; ++f) {
        float mt = fmaxf(pmax[f], __shfl_xor(pmax[f], 16));
        mt = fmaxf(mt, __shfl_xor(mt, 32));
        const float mnew = fmaxf(mrun[f], mt);
        const float alpha = exp2f(CEXP * (mrun[f] - mnew));
        lsum[f] *= alpha;
#pragma unroll
        for (int fd = 0; fd < 4; ++fd)
#pragma unroll
          for (int j = 0; j < 4; ++j) o[fd][f][j] *= alpha;
        mrun[f] = mnew;
      }
    }
    unsigned pk[4][2][2];
#pragma unroll
    for (int f = 0; f < 2; ++f) {
      const float negcm = -CEXP * mrun[f];
      float ts = 0.f;
#pragma unroll
      for (int fk = 0; fk < 4; ++fk)
#pragma unroll
        for (int jp = 0; jp < 2; ++jp) {
          const float p0 = exp2f(fmaf(st[fk][f][2 * jp], CEXP, negcm));
          const float p1 = exp2f(fmaf(st[fk][f][2 * jp + 1], CEXP, negcm));
          ts += p0 + p1;
          union { bf16 h2[2]; unsigned u; } cv;
          cv.h2[0] = (bf16)p0;
          cv.h2[1] = (bf16)p1;
          pk[fk][f][jp] = cv.u;
        }
      lsum[f] += ts;
    }
    // ---- P^T -> B-frag-linear LDS (8x b64 write) ----
#pragma unroll
    for (int fk = 0; fk < 4; ++fk) {
      u32x2 w0, w1;
      w0[0] = pk[fk][0][0]; w0[1] = pk[fk][0][1];
      w1[0] = pk[fk][1][0]; w1[1] = pk[fk][1][1];
      *(u32x2*)(pw + paddr[fk]) = w0;
      *(u32x2*)(pw + paddr[fk] + 1024) = w1;
    }
    bf16x8 pa[2][2];
#pragma unroll
    for (int f = 0; f < 2; ++f)
#pragma unroll
      for (int ksl = 0; ksl < 2; ++ksl)
        pa[f][ksl] = *(const bf16x8*)(prd + ksl * 2048 + f * 1024);
    // ---- O^T += V^T · P^T ----
    const char* vb = (const char*)&Vl[0][0] + slot * 8192 + lane * 16;
    __builtin_amdgcn_s_setprio(1);
#pragma unroll
    for (int fd = 0; fd < 4; ++fd) {
      const bf16x8 v0 = *(const bf16x8*)(vb + fd * 2048);
      const bf16x8 v1 = *(const bf16x8*)(vb + fd * 2048 + 1024);
#pragma unroll
      for (int f = 0; f < 2; ++f) {
        o[fd][f] = __builtin_amdgcn_mfma_f32_16x16x32_bf16(v0, pa[f][0], o[fd][f], 0, 0, 0);
        o[fd][f] = __builtin_amdgcn_mfma_f32_16x16x32_bf16(v1, pa[f][1], o[fd][f], 0, 0, 0);
      }
    }
    __builtin_amdgcn_s_setprio(0);
    // ---- producer waits (counted) BEFORE barrier; prefetch stays in flight ----
    if (t < 30) {
      asm volatile("s_waitcnt vmcnt(4)" ::: "memory");
    } else {
      asm volatile("s_waitcnt vmcnt(0)" ::: "memory");
    }
    __builtin_amdgcn_s_barrier();
    slot = (slot == 2) ? 0 : slot + 1;
    slot2 = (slot2 == 2) ? 0 : slot2 + 1;
  }

  // epilogue: reduce lsum across g-groups (kv slices), then store O^T
#pragma unroll
  for (int f = 0; f < 2; ++f) {
    float l = lsum[f];
    l += __shfl_xor(l, 16);
    l += __shfl_xor(l, 32);
    lsum[f] = 1.0f / l;
  }
#pragma unroll
  for (int f = 0; f < 2; ++f) {
    bf16* const orow = ob + (qrow0 + f * 16) * 256 + h * 64 + g * 4;
#pragma unroll
    for (int fd = 0; fd < 4; ++fd) {
      bf16x4 ov;
#pragma unroll
      for (int j = 0; j < 4; ++j) ov[j] = (bf16)(o[fd][f][j] * lsum[f]);
      *(bf16x4*)(orow + fd * 16) = ov;
    }
  }
}

extern "C" void kernel_launch(void* const* d_in, const int* in_sizes, int n_in,
                              void* d_out, int out_size, void* d_ws, size_t ws_size,
                              hipStream_t stream) {
  const float* x      = (const float*)d_in[0];
  const float* qkv_w  = (const float*)d_in[1];
  const float* qkv_b  = (const float*)d_in[2];
  const float* proj_w = (const float*)d_in[3];
  const float* proj_b = (const float*)d_in[4];
  const float* ln1_g  = (const float*)d_in[5];
  const float* ln1_b  = (const float*)d_in[6];
  const float* ln2_g  = (const float*)d_in[7];
  const float* ln2_b  = (const float*)d_in[8];
  const float* mlp_w1 = (const float*)d_in[9];
  const float* mlp_b1 = (const float*)d_in[10];
  const float* mlp_w2 = (const float*)d_in[11];
  const float* mlp_b2 = (const float*)d_in[12];
  float* out = (float*)d_out;

  char* ws = (char*)d_ws;
  bf16* Wtqkv = (bf16*)(ws);              // [768][256]   393216 B
  bf16* WtP   = (bf16*)(ws + 393216);     // [256][256]   131072 B
  bf16* Wt1   = (bf16*)(ws + 524288);     // [512][256]   262144 B
  bf16* Wt2   = (bf16*)(ws + 786432);     // [256][512]   262144 B
  bf16* h     = (bf16*)(ws + 1048576);    // [16384][256] 8388608 B
  bf16* qkb   = (bf16*)(ws + 9437184);    // [16384][512] 16777216 B
  bf16* vT    = (bf16*)(ws + 26214400);   // [32][64][2048] 8388608 B
  bf16* obuf  = (bf16*)(ws + 34603008);   // [16384][256] 8388608 B
  float* x2   = (float*)(ws + 42991616);  // [16384][256] 16777216 B  (total 59.8 MB)
  bf16* a1 = qkb;  // reuse (qkb dead after attn)
  bf16* h2 = h;    // reuse (h dead after V gemm)

  wconv_all<<<2048, 256, 0, stream>>>(qkv_w, proj_w, mlp_w1, mlp_w2, Wtqkv, WtP, Wt1, Wt2);

  ln_fwd<<<4096, 256, 0, stream>>>(x, ln1_g, ln1_b, h);
  // Q,K: h @ W_qk  -> qkb [16384][512]
  gemm_bt<0><<<512, 256, 0, stream>>>(h, Wtqkv, qkv_b, nullptr, qkb, 16384, 512, 256);
  // V^T: Wv^T @ h^T -> vT [32][64][2048]  (swapped-operand GEMM, scatter epilogue)
  gemm_bt<1><<<256, 256, 0, stream>>>(Wtqkv + 512 * 256, h, qkv_b + 512, nullptr, vT, 256, 16384, 256);
  attn_fwd<<<512, 256, 0, stream>>>(qkb, vT, obuf);
  // proj + residual -> x2 (f32)
  gemm_bt<2><<<256, 256, 0, stream>>>(obuf, WtP, proj_b, x, x2, 16384, 256, 256);
  ln_fwd<<<4096, 256, 0, stream>>>(x2, ln2_g, ln2_b, h2);
  // fc1 + gelu -> a1 (bf16)
  gemm_bt<3><<<512, 256, 0, stream>>>(h2, Wt1, mlp_b1, nullptr, a1, 16384, 512, 256);
  // fc2 + residual -> out (f32)
  gemm_bt<2><<<256, 256, 0, stream>>>(a1, Wt2, mlp_b2, x2, out, 16384, 256, 512);
}